// Round 1
// baseline (10081.318 us; speedup 1.0000x reference)
//
#include <hip/hip_runtime.h>
#include <cmath>

#define B_ 4
#define F_ 8
#define P_ 196
#define D_ 768
#define H_ 12
#define HD_ 64
#define L_ 4
#define MLP_ 3072
#define N_ (1 + F_*P_)     // 1569
#define BN_ (B_*N_)        // 6276
#define SCALE_ 0.125f
#define QKVC_ (3*D_)       // 2304

// ---------------------------------------------------------------- LayerNorm
__global__ __launch_bounds__(256) void ln_kernel(const float* __restrict__ x,
                                                 const float* __restrict__ g,
                                                 const float* __restrict__ b,
                                                 float* __restrict__ out) {
  int row = blockIdx.x;
  const float* xr = x + (size_t)row * D_;
  float* orow = out + (size_t)row * D_;
  int tid = threadIdx.x;
  float v0 = xr[tid], v1 = xr[tid + 256], v2 = xr[tid + 512];
  float s  = v0 + v1 + v2;
  float ss = v0*v0 + v1*v1 + v2*v2;
  #pragma unroll
  for (int o = 32; o > 0; o >>= 1) { s += __shfl_xor(s, o); ss += __shfl_xor(ss, o); }
  __shared__ float sm[8];
  int w = tid >> 6;
  if ((tid & 63) == 0) { sm[w*2] = s; sm[w*2+1] = ss; }
  __syncthreads();
  float tot  = sm[0] + sm[2] + sm[4] + sm[6];
  float tot2 = sm[1] + sm[3] + sm[5] + sm[7];
  float mean = tot * (1.0f/D_);
  float var  = tot2 * (1.0f/D_) - mean*mean;
  float rs   = rsqrtf(var + 1e-5f);
  orow[tid]       = (v0 - mean)*rs*g[tid]       + b[tid];
  orow[tid + 256] = (v1 - mean)*rs*g[tid + 256] + b[tid + 256];
  orow[tid + 512] = (v2 - mean)*rs*g[tid + 512] + b[tid + 512];
}

// ---------------------------------------------------------------- GEMM
// C[M,NN] = A[M,K] @ W[NN,K]^T  (+ epilogue)
// EPI 0: none.  EPI 1: + bias + Res.  EPI 2: gelu(+ bias)
__device__ __forceinline__ float gelu_exact(float x) {
  return 0.5f * x * (1.0f + erff(x * 0.70710678118654752f));
}

template<int EPI>
__global__ __launch_bounds__(256) void gemm_kernel(const float* __restrict__ A,
                                                   const float* __restrict__ W,
                                                   const float* __restrict__ bias,
                                                   const float* __restrict__ Res,
                                                   float* __restrict__ C,
                                                   int M, int NN, int K) {
  __shared__ __align__(16) float As[16][64];
  __shared__ __align__(16) float Ws[16][64];
  int tid = threadIdx.x;
  int m0 = blockIdx.x * 64;
  int n0 = blockIdx.y * 64;
  int lr = tid >> 2;          // 0..63
  int lc = (tid & 3) << 2;    // 0,4,8,12
  int tx = tid & 15, ty = tid >> 4;
  float acc[4][4] = {};
  for (int k0 = 0; k0 < K; k0 += 16) {
    int arow = m0 + lr;
    float4 av = make_float4(0.f, 0.f, 0.f, 0.f);
    if (arow < M) av = *(const float4*)&A[(size_t)arow * K + k0 + lc];
    float4 wv = *(const float4*)&W[(size_t)(n0 + lr) * K + k0 + lc];
    __syncthreads();
    As[lc+0][lr] = av.x; As[lc+1][lr] = av.y; As[lc+2][lr] = av.z; As[lc+3][lr] = av.w;
    Ws[lc+0][lr] = wv.x; Ws[lc+1][lr] = wv.y; Ws[lc+2][lr] = wv.z; Ws[lc+3][lr] = wv.w;
    __syncthreads();
    #pragma unroll
    for (int kk = 0; kk < 16; ++kk) {
      float4 a = *(const float4*)&As[kk][ty << 2];
      float4 b = *(const float4*)&Ws[kk][tx << 2];
      float ar[4] = {a.x, a.y, a.z, a.w};
      float br[4] = {b.x, b.y, b.z, b.w};
      #pragma unroll
      for (int i = 0; i < 4; ++i)
        #pragma unroll
        for (int j = 0; j < 4; ++j)
          acc[i][j] = fmaf(ar[i], br[j], acc[i][j]);
    }
  }
  int crow = m0 + (ty << 2);
  int ccol = n0 + (tx << 2);
  float bv[4] = {0.f, 0.f, 0.f, 0.f};
  if (EPI >= 1) {
    bv[0] = bias[ccol+0]; bv[1] = bias[ccol+1]; bv[2] = bias[ccol+2]; bv[3] = bias[ccol+3];
  }
  #pragma unroll
  for (int i = 0; i < 4; ++i) {
    int row = crow + i;
    if (row < M) {
      float vals[4];
      float4 rv = make_float4(0.f, 0.f, 0.f, 0.f);
      if (EPI == 1) rv = *(const float4*)&Res[(size_t)row * NN + ccol];
      float rr[4] = {rv.x, rv.y, rv.z, rv.w};
      #pragma unroll
      for (int j = 0; j < 4; ++j) {
        float v = acc[i][j] + bv[j];
        if (EPI == 1) v += rr[j];
        if (EPI == 2) v = gelu_exact(v);
        vals[j] = v;
      }
      *(float4*)&C[(size_t)row * NN + ccol] = make_float4(vals[0], vals[1], vals[2], vals[3]);
    }
  }
}

// ---------------------------------------------------------------- cls attention
// One block per (b,h). Query = token 0, keys = all N tokens.
__global__ __launch_bounds__(256) void cls_attn_kernel(const float* __restrict__ qkv,
                                                       float* __restrict__ att) {
  int bh = blockIdx.x;
  int b = bh / H_, h = bh % H_;
  const float* base = qkv + (size_t)b * N_ * QKVC_ + h * HD_;
  __shared__ float q[HD_];
  __shared__ float s[N_];
  __shared__ float red[8];
  __shared__ float pv[4][HD_];
  int tid = threadIdx.x;
  if (tid < HD_) q[tid] = base[tid] * SCALE_;
  __syncthreads();
  float lmax = -1e30f;
  for (int j = tid; j < N_; j += 256) {
    const float* kp = base + (size_t)j * QKVC_ + D_;
    float acc = 0.f;
    #pragma unroll
    for (int d = 0; d < HD_; d += 4) {
      float4 kv = *(const float4*)&kp[d];
      acc += q[d]*kv.x + q[d+1]*kv.y + q[d+2]*kv.z + q[d+3]*kv.w;
    }
    s[j] = acc;
    lmax = fmaxf(lmax, acc);
  }
  #pragma unroll
  for (int o = 32; o > 0; o >>= 1) lmax = fmaxf(lmax, __shfl_xor(lmax, o));
  if ((tid & 63) == 0) red[tid >> 6] = lmax;
  __syncthreads();
  float m = fmaxf(fmaxf(red[0], red[1]), fmaxf(red[2], red[3]));
  float lsum = 0.f;
  for (int j = tid; j < N_; j += 256) { float p = __expf(s[j] - m); s[j] = p; lsum += p; }
  #pragma unroll
  for (int o = 32; o > 0; o >>= 1) lsum += __shfl_xor(lsum, o);
  if ((tid & 63) == 0) red[4 + (tid >> 6)] = lsum;
  __syncthreads();
  float denom = red[4] + red[5] + red[6] + red[7];
  int d = tid & 63, gidx = tid >> 6;
  float acc = 0.f;
  for (int j = gidx; j < N_; j += 4)
    acc += s[j] * base[(size_t)j * QKVC_ + 2*D_ + d];
  pv[gidx][d] = acc;
  __syncthreads();
  if (gidx == 0) {
    att[(size_t)(b * N_) * D_ + h * HD_ + d] = (pv[0][d] + pv[1][d] + pv[2][d] + pv[3][d]) / denom;
  }
}

// ---------------------------------------------------------------- space attention
// One block per (bh, f): 196 queries over 197 keys (cls + frame patches).
__global__ __launch_bounds__(256) void space_attn_kernel(const float* __restrict__ qkv,
                                                         float* __restrict__ att) {
  int blk = blockIdx.x;          // bh*F + f
  int f = blk % F_, bh = blk / F_;
  int b = bh / H_, h = bh % H_;
  const float* base = qkv + (size_t)b * N_ * QKVC_ + h * HD_;
  __shared__ float Ks[197][65];
  __shared__ float qs[4][HD_];
  __shared__ float ps[4][200];
  int tid = threadIdx.x;
  for (int idx = tid; idx < 197 * 64; idx += 256) {
    int j = idx >> 6, d = idx & 63;
    int n = (j == 0) ? 0 : (1 + f * P_ + j - 1);
    Ks[j][d] = base[(size_t)n * QKVC_ + D_ + d];
  }
  __syncthreads();
  int w = tid >> 6, lane = tid & 63;
  for (int q = w; q < P_; q += 4) {        // exactly 49 iterations per wave
    int n = 1 + f * P_ + q;
    qs[w][lane] = base[(size_t)n * QKVC_ + lane] * SCALE_;
    __syncthreads();
    int j0 = lane, j1 = lane + 64, j2 = lane + 128, j3 = lane + 192;
    bool has3 = (j3 < 197);
    int j3c = has3 ? j3 : 0;
    float a0 = 0.f, a1 = 0.f, a2 = 0.f, a3 = 0.f;
    #pragma unroll 8
    for (int d = 0; d < HD_; ++d) {
      float qd = qs[w][d];
      a0 = fmaf(qd, Ks[j0][d], a0);
      a1 = fmaf(qd, Ks[j1][d], a1);
      a2 = fmaf(qd, Ks[j2][d], a2);
      a3 = fmaf(qd, Ks[j3c][d], a3);
    }
    float lmax = fmaxf(fmaxf(a0, a1), a2);
    if (has3) lmax = fmaxf(lmax, a3);
    #pragma unroll
    for (int o = 32; o > 0; o >>= 1) lmax = fmaxf(lmax, __shfl_xor(lmax, o));
    float p0 = __expf(a0 - lmax), p1 = __expf(a1 - lmax), p2 = __expf(a2 - lmax);
    float p3 = has3 ? __expf(a3 - lmax) : 0.f;
    ps[w][j0] = p0; ps[w][j1] = p1; ps[w][j2] = p2;
    if (has3) ps[w][j3] = p3;
    float lsum = p0 + p1 + p2 + p3;
    #pragma unroll
    for (int o = 32; o > 0; o >>= 1) lsum += __shfl_xor(lsum, o);
    __syncthreads();
    // PV: lane = output dim d, V read coalesced from global (L1-hot)
    float acc = ps[w][0] * base[2*D_ + lane];             // cls value (token 0)
    for (int j = 1; j < 197; ++j) {
      int nk = 1 + f * P_ + j - 1;
      acc = fmaf(ps[w][j], base[(size_t)nk * QKVC_ + 2*D_ + lane], acc);
    }
    att[(size_t)(b * N_ + n) * D_ + h * HD_ + lane] = acc / lsum;
    __syncthreads();
  }
}

// ---------------------------------------------------------------- time attention
// One wave per (bh, p): 8 queries (frames) over 9 keys (cls + 8 frames).
__global__ __launch_bounds__(256) void time_attn_kernel(const float* __restrict__ qkv,
                                                        float* __restrict__ att) {
  int idx = blockIdx.x * 4 + (threadIdx.x >> 6);   // (bh, p) index, exact
  int bh = idx / P_, p = idx % P_;
  int b = bh / H_, h = bh % H_;
  int lane = threadIdx.x & 63;
  const float* base = qkv + (size_t)b * N_ * QKVC_ + h * HD_ + lane;
  float k[9], v[9];
  k[0] = base[D_];
  v[0] = base[2*D_];
  #pragma unroll
  for (int j = 0; j < 8; ++j) {
    size_t r = (size_t)(1 + j * P_ + p) * QKVC_;
    k[j+1] = base[r + D_];
    v[j+1] = base[r + 2*D_];
  }
  #pragma unroll 1
  for (int f = 0; f < F_; ++f) {
    size_t qr = (size_t)(1 + f * P_ + p) * QKVC_;
    float qd = base[qr] * SCALE_;
    float s[9];
    #pragma unroll
    for (int j = 0; j < 9; ++j) {
      float prod = qd * k[j];
      #pragma unroll
      for (int o = 32; o > 0; o >>= 1) prod += __shfl_xor(prod, o);
      s[j] = prod;
    }
    float m = s[0];
    #pragma unroll
    for (int j = 1; j < 9; ++j) m = fmaxf(m, s[j]);
    float den = 0.f, o_ = 0.f;
    #pragma unroll
    for (int j = 0; j < 9; ++j) {
      float pj = __expf(s[j] - m);
      den += pj;
      o_ = fmaf(pj, v[j], o_);
    }
    att[(size_t)(b * N_ + 1 + f * P_ + p) * D_ + h * HD_ + lane] = o_ / den;
  }
}

// ---------------------------------------------------------------- launcher
extern "C" void kernel_launch(void* const* d_in, const int* in_sizes, int n_in,
                              void* d_out, int out_size, void* d_ws, size_t ws_size,
                              hipStream_t stream) {
  const float* x_in     = (const float*)d_in[0];
  const float* qkv_w_t  = (const float*)d_in[1];
  const float* proj_w_t = (const float*)d_in[2];
  const float* proj_b_t = (const float*)d_in[3];
  const float* qkv_w_s  = (const float*)d_in[4];
  const float* proj_w_s = (const float*)d_in[5];
  const float* proj_b_s = (const float*)d_in[6];
  const float* fc1_w    = (const float*)d_in[7];
  const float* fc1_b    = (const float*)d_in[8];
  const float* fc2_w    = (const float*)d_in[9];
  const float* fc2_b    = (const float*)d_in[10];
  const float* ln1_g    = (const float*)d_in[11];
  const float* ln1_b    = (const float*)d_in[12];
  const float* ln2_g    = (const float*)d_in[13];
  const float* ln2_b    = (const float*)d_in[14];
  const float* ln3_g    = (const float*)d_in[15];
  const float* ln3_b    = (const float*)d_in[16];

  float* X_out = (float*)d_out;
  float* ws = (float*)d_ws;
  const size_t SZ = (size_t)BN_ * D_;
  float* A   = ws;            // LN output (aliases ATT — disjoint lifetimes)
  float* ATT = ws;            // attention output
  float* TR  = ws + SZ;       // time_residual, then space_residual
  float* BIG = ws + 2 * SZ;   // qkv (BN x 2304) / mlp hidden (BN x 3072)

  dim3 blk(256);
  dim3 g_qkv(99, 36), g_proj(99, 12), g_fc1(99, 48), g_fc2(99, 12);

  for (int l = 0; l < L_; ++l) {
    const float* X = (l == 0) ? x_in : (const float*)X_out;
    // 1. a = LN3(x)
    ln_kernel<<<BN_, blk, 0, stream>>>(X, ln3_g + l*D_, ln3_b + l*D_, A);
    // 2. qkv_t = a @ qkv_w_t^T
    gemm_kernel<0><<<g_qkv, blk, 0, stream>>>(A, qkv_w_t + (size_t)l*3*D_*D_, nullptr, nullptr, BIG, BN_, QKVC_, D_);
    // 3/4. time attention (+ cls)
    cls_attn_kernel<<<B_*H_, blk, 0, stream>>>(BIG, ATT);
    time_attn_kernel<<<(B_*H_*P_)/4, blk, 0, stream>>>(BIG, ATT);
    // 5. time_residual = x + att @ proj_w_t^T + b
    gemm_kernel<1><<<g_proj, blk, 0, stream>>>(ATT, proj_w_t + (size_t)l*D_*D_, proj_b_t + l*D_, X, TR, BN_, D_, D_);
    // 6. a = LN1(time_residual)
    ln_kernel<<<BN_, blk, 0, stream>>>(TR, ln1_g + l*D_, ln1_b + l*D_, A);
    // 7. qkv_s
    gemm_kernel<0><<<g_qkv, blk, 0, stream>>>(A, qkv_w_s + (size_t)l*3*D_*D_, nullptr, nullptr, BIG, BN_, QKVC_, D_);
    // 8/9. space attention (+ cls)
    cls_attn_kernel<<<B_*H_, blk, 0, stream>>>(BIG, ATT);
    space_attn_kernel<<<B_*H_*F_, blk, 0, stream>>>(BIG, ATT);
    // 10. space_residual = x + att @ proj_w_s^T + b   (into TR)
    gemm_kernel<1><<<g_proj, blk, 0, stream>>>(ATT, proj_w_s + (size_t)l*D_*D_, proj_b_s + l*D_, X, TR, BN_, D_, D_);
    // 11. a = LN2(space_residual)
    ln_kernel<<<BN_, blk, 0, stream>>>(TR, ln2_g + l*D_, ln2_b + l*D_, A);
    // 12. h = gelu(a @ fc1^T + b)
    gemm_kernel<2><<<g_fc1, blk, 0, stream>>>(A, fc1_w + (size_t)l*MLP_*D_, fc1_b + l*MLP_, nullptr, BIG, BN_, MLP_, D_);
    // 13. out = space_residual + h @ fc2^T + b
    gemm_kernel<1><<<g_fc2, blk, 0, stream>>>(BIG, fc2_w + (size_t)l*D_*MLP_, fc2_b + l*D_, TR, X_out, BN_, D_, MLP_);
  }
}

// Round 2
// 3640.616 us; speedup vs baseline: 2.7691x; 2.7691x over previous
//
#include <hip/hip_runtime.h>
#include <cmath>

#define B_ 4
#define F_ 8
#define P_ 196
#define D_ 768
#define H_ 12
#define HD_ 64
#define L_ 4
#define MLP_ 3072
#define N_ (1 + F_*P_)     // 1569
#define BN_ (B_*N_)        // 6276
#define SCALE_ 0.125f
#define QKVC_ (3*D_)       // 2304

typedef __bf16 bf16x8 __attribute__((ext_vector_type(8)));
typedef float f32x4 __attribute__((ext_vector_type(4)));
typedef const __attribute__((address_space(1))) void* gas_ptr;
typedef __attribute__((address_space(3))) void* las_ptr;

__device__ __forceinline__ unsigned short f2bf(float f) {
  union { __bf16 b; unsigned short u; } cv;
  cv.b = (__bf16)f;
  return cv.u;
}

__device__ __forceinline__ float gelu_exact(float x) {
  return 0.5f * x * (1.0f + erff(x * 0.70710678118654752f));
}

// ---------------------------------------------------------------- weight convert (per layer)
#define SQKV 1769472
#define SPROJ 589824
#define SFC 2359296

__device__ __forceinline__ void cvt_seg(const float* __restrict__ src,
                                        unsigned short* __restrict__ dst,
                                        int n, int t0, int stride) {
  for (int i = t0; i < (n >> 2); i += stride) {
    float4 v = ((const float4*)src)[i];
    ushort4 o;
    o.x = f2bf(v.x); o.y = f2bf(v.y); o.z = f2bf(v.z); o.w = f2bf(v.w);
    ((ushort4*)dst)[i] = o;
  }
}

__global__ __launch_bounds__(256) void cvt_layer_kernel(const float* qt, const float* pt,
                                                        const float* qs, const float* ps,
                                                        const float* f1, const float* f2,
                                                        unsigned short* wb) {
  int t0 = blockIdx.x * blockDim.x + threadIdx.x;
  int stride = gridDim.x * blockDim.x;
  cvt_seg(qt, wb + 0,       SQKV,  t0, stride);
  cvt_seg(pt, wb + 1769472, SPROJ, t0, stride);
  cvt_seg(qs, wb + 2359296, SQKV,  t0, stride);
  cvt_seg(ps, wb + 4128768, SPROJ, t0, stride);
  cvt_seg(f1, wb + 4718592, SFC,   t0, stride);
  cvt_seg(f2, wb + 7077888, SFC,   t0, stride);
}

// ---------------------------------------------------------------- LayerNorm (fp32 in, bf16 out)
__global__ __launch_bounds__(256) void ln_kernel(const float* __restrict__ x,
                                                 const float* __restrict__ g,
                                                 const float* __restrict__ b,
                                                 unsigned short* __restrict__ out) {
  int row = blockIdx.x;
  const float* xr = x + (size_t)row * D_;
  unsigned short* orow = out + (size_t)row * D_;
  int tid = threadIdx.x;
  float v0 = xr[tid], v1 = xr[tid + 256], v2 = xr[tid + 512];
  float s  = v0 + v1 + v2;
  float ss = v0*v0 + v1*v1 + v2*v2;
  #pragma unroll
  for (int o = 32; o > 0; o >>= 1) { s += __shfl_xor(s, o); ss += __shfl_xor(ss, o); }
  __shared__ float sm[8];
  int w = tid >> 6;
  if ((tid & 63) == 0) { sm[w*2] = s; sm[w*2+1] = ss; }
  __syncthreads();
  float tot  = sm[0] + sm[2] + sm[4] + sm[6];
  float tot2 = sm[1] + sm[3] + sm[5] + sm[7];
  float mean = tot * (1.0f/D_);
  float var  = tot2 * (1.0f/D_) - mean*mean;
  float rs   = rsqrtf(var + 1e-5f);
  orow[tid]       = f2bf((v0 - mean)*rs*g[tid]       + b[tid]);
  orow[tid + 256] = f2bf((v1 - mean)*rs*g[tid + 256] + b[tid + 256]);
  orow[tid + 512] = f2bf((v2 - mean)*rs*g[tid + 512] + b[tid + 512]);
}

// ---------------------------------------------------------------- MFMA GEMM
// C[M,NN] = A[M,K](bf16) @ W[NN,K](bf16)^T, fp32 accumulate.
// EPI 0: none (fp32 out). EPI 1: +bias +Res (fp32 out). EPI 2: gelu(+bias) (bf16 out)
template<int EPI>
__global__ __launch_bounds__(256) void mfma_gemm(const unsigned short* __restrict__ A,
                                                 const unsigned short* __restrict__ W,
                                                 const float* __restrict__ bias,
                                                 const float* __restrict__ Res,
                                                 void* __restrict__ Cout,
                                                 int M, int NN, int K) {
  __shared__ __align__(16) unsigned short As[128*32];
  __shared__ __align__(16) unsigned short Bs[128*32];
  int tid = threadIdx.x;
  int w = tid >> 6, l = tid & 63;
  int m0 = blockIdx.x * 128, n0 = blockIdx.y * 128;
  int wr = w >> 1, wc = w & 1;

  // staging: chunk c covers 16B at LDS byte-offset c*16; row=c/4, col(bf16)=(c%4)*8
  int c0 = tid, c1 = tid + 256;
  int rA0 = c0 >> 2, kA0 = (c0 & 3) << 3;
  int rA1 = c1 >> 2, kA1 = (c1 & 3) << 3;
  int mr0 = m0 + rA0; if (mr0 >= M) mr0 = M - 1;
  int mr1 = m0 + rA1; if (mr1 >= M) mr1 = M - 1;
  const unsigned short* gA0 = A + (size_t)mr0 * K + kA0;
  const unsigned short* gA1 = A + (size_t)mr1 * K + kA1;
  const unsigned short* gB0 = W + (size_t)(n0 + rA0) * K + kA0;
  const unsigned short* gB1 = W + (size_t)(n0 + rA1) * K + kA1;
  unsigned short* lA0 = &As[(size_t)(w*64)*8];
  unsigned short* lA1 = &As[(size_t)(256 + w*64)*8];
  unsigned short* lB0 = &Bs[(size_t)(w*64)*8];
  unsigned short* lB1 = &Bs[(size_t)(256 + w*64)*8];

  int fr = l & 15, fq = l >> 4;   // frag row, k-quarter
  f32x4 acc[4][4] = {};

  for (int k0 = 0; k0 < K; k0 += 32) {
    __builtin_amdgcn_global_load_lds((gas_ptr)(gA0 + k0), (las_ptr)lA0, 16, 0, 0);
    __builtin_amdgcn_global_load_lds((gas_ptr)(gA1 + k0), (las_ptr)lA1, 16, 0, 0);
    __builtin_amdgcn_global_load_lds((gas_ptr)(gB0 + k0), (las_ptr)lB0, 16, 0, 0);
    __builtin_amdgcn_global_load_lds((gas_ptr)(gB1 + k0), (las_ptr)lB1, 16, 0, 0);
    __syncthreads();
    bf16x8 af[4], bf[4];
    #pragma unroll
    for (int i = 0; i < 4; ++i)
      af[i] = *(const bf16x8*)&As[(wr*64 + i*16 + fr)*32 + fq*8];
    #pragma unroll
    for (int j = 0; j < 4; ++j)
      bf[j] = *(const bf16x8*)&Bs[(wc*64 + j*16 + fr)*32 + fq*8];
    #pragma unroll
    for (int i = 0; i < 4; ++i)
      #pragma unroll
      for (int j = 0; j < 4; ++j)
        acc[i][j] = __builtin_amdgcn_mfma_f32_16x16x32_bf16(af[i], bf[j], acc[i][j], 0, 0, 0);
    __syncthreads();
  }

  // epilogue: C/D layout col = l&15, row = (l>>4)*4 + reg  [m89-verified]
  #pragma unroll
  for (int j = 0; j < 4; ++j) {
    int col = n0 + wc*64 + j*16 + fr;
    float bj = (EPI >= 1) ? bias[col] : 0.f;
    #pragma unroll
    for (int i = 0; i < 4; ++i) {
      int rowb = m0 + wr*64 + i*16 + fq*4;
      #pragma unroll
      for (int r = 0; r < 4; ++r) {
        int row = rowb + r;
        if (row < M) {
          float v = acc[i][j][r] + bj;
          if (EPI == 1) v += Res[(size_t)row * NN + col];
          if (EPI == 2) {
            ((unsigned short*)Cout)[(size_t)row * NN + col] = f2bf(gelu_exact(v));
          } else {
            ((float*)Cout)[(size_t)row * NN + col] = v;
          }
        }
      }
    }
  }
}

// ---------------------------------------------------------------- cls attention
__global__ __launch_bounds__(256) void cls_attn_kernel(const float* __restrict__ qkv,
                                                       unsigned short* __restrict__ att) {
  int bh = blockIdx.x;
  int b = bh / H_, h = bh % H_;
  const float* base = qkv + (size_t)b * N_ * QKVC_ + h * HD_;
  __shared__ float q[HD_];
  __shared__ float s[N_];
  __shared__ float red[8];
  __shared__ float pv[4][HD_];
  int tid = threadIdx.x;
  if (tid < HD_) q[tid] = base[tid] * SCALE_;
  __syncthreads();
  float lmax = -1e30f;
  for (int j = tid; j < N_; j += 256) {
    const float* kp = base + (size_t)j * QKVC_ + D_;
    float acc = 0.f;
    #pragma unroll
    for (int d = 0; d < HD_; d += 4) {
      float4 kv = *(const float4*)&kp[d];
      acc += q[d]*kv.x + q[d+1]*kv.y + q[d+2]*kv.z + q[d+3]*kv.w;
    }
    s[j] = acc;
    lmax = fmaxf(lmax, acc);
  }
  #pragma unroll
  for (int o = 32; o > 0; o >>= 1) lmax = fmaxf(lmax, __shfl_xor(lmax, o));
  if ((tid & 63) == 0) red[tid >> 6] = lmax;
  __syncthreads();
  float m = fmaxf(fmaxf(red[0], red[1]), fmaxf(red[2], red[3]));
  float lsum = 0.f;
  for (int j = tid; j < N_; j += 256) { float p = __expf(s[j] - m); s[j] = p; lsum += p; }
  #pragma unroll
  for (int o = 32; o > 0; o >>= 1) lsum += __shfl_xor(lsum, o);
  if ((tid & 63) == 0) red[4 + (tid >> 6)] = lsum;
  __syncthreads();
  float denom = red[4] + red[5] + red[6] + red[7];
  int d = tid & 63, gidx = tid >> 6;
  float acc = 0.f;
  for (int j = gidx; j < N_; j += 4)
    acc += s[j] * base[(size_t)j * QKVC_ + 2*D_ + d];
  pv[gidx][d] = acc;
  __syncthreads();
  if (gidx == 0) {
    att[(size_t)(b * N_) * D_ + h * HD_ + d] = f2bf((pv[0][d] + pv[1][d] + pv[2][d] + pv[3][d]) / denom);
  }
}

// ---------------------------------------------------------------- space attention
// blocks = (bh,f,half): 98 queries over 197 keys. Waves independent (no lockstep).
__global__ __launch_bounds__(512) void space_attn_kernel(const float* __restrict__ qkv,
                                                         unsigned short* __restrict__ att) {
  int blk = blockIdx.x;
  int half = blk & 1;
  int bhf = blk >> 1;
  int f = bhf % F_, bh = bhf / F_;
  int b = bh / H_, h = bh % H_;
  const float* base = qkv + (size_t)b * N_ * QKVC_ + h * HD_;
  __shared__ float Ks[197][65];
  __shared__ float Vs[64][201];
  __shared__ float ps[8][200];
  int tid = threadIdx.x;
  for (int idx = tid; idx < 197 * 64; idx += 512) {
    int j = idx >> 6, d = idx & 63;
    int n = (j == 0) ? 0 : (1 + f * P_ + j - 1);
    const float* r = base + (size_t)n * QKVC_;
    Ks[j][d] = r[D_ + d];
    Vs[d][j] = r[2*D_ + d];
  }
  __syncthreads();
  int w = tid >> 6, lane = tid & 63;
  int j0 = lane, j1 = lane + 64, j2 = lane + 128, j3v = lane + 192;
  bool has3 = (j3v < 197);
  int j3 = has3 ? j3v : 0;
  int qbeg = half * 98 + w, qend = half * 98 + 98;
  for (int q = qbeg; q < qend; q += 8) {
    int n = 1 + f * P_ + q;
    float qreg = base[(size_t)n * QKVC_ + lane] * SCALE_;
    float a0 = 0.f, a1 = 0.f, a2 = 0.f, a3 = 0.f;
    #pragma unroll
    for (int d0 = 0; d0 < HD_; d0 += 4) {
      float q0 = __shfl(qreg, d0+0), q1 = __shfl(qreg, d0+1);
      float q2 = __shfl(qreg, d0+2), q3 = __shfl(qreg, d0+3);
      float4 k0v = *(const float4*)&Ks[j0][d0];
      float4 k1v = *(const float4*)&Ks[j1][d0];
      float4 k2v = *(const float4*)&Ks[j2][d0];
      float4 k3v = *(const float4*)&Ks[j3][d0];
      a0 = fmaf(q0,k0v.x,fmaf(q1,k0v.y,fmaf(q2,k0v.z,fmaf(q3,k0v.w,a0))));
      a1 = fmaf(q0,k1v.x,fmaf(q1,k1v.y,fmaf(q2,k1v.z,fmaf(q3,k1v.w,a1))));
      a2 = fmaf(q0,k2v.x,fmaf(q1,k2v.y,fmaf(q2,k2v.z,fmaf(q3,k2v.w,a2))));
      a3 = fmaf(q0,k3v.x,fmaf(q1,k3v.y,fmaf(q2,k3v.z,fmaf(q3,k3v.w,a3))));
    }
    float lmax = fmaxf(fmaxf(a0, a1), a2);
    if (has3) lmax = fmaxf(lmax, a3);
    #pragma unroll
    for (int o = 32; o > 0; o >>= 1) lmax = fmaxf(lmax, __shfl_xor(lmax, o));
    float p0 = __expf(a0 - lmax), p1 = __expf(a1 - lmax), p2 = __expf(a2 - lmax);
    float p3 = has3 ? __expf(a3 - lmax) : 0.f;
    ps[w][j0] = p0; ps[w][j1] = p1; ps[w][j2] = p2;
    if (has3) ps[w][j3v] = p3;
    float lsum = p0 + p1 + p2 + p3;
    #pragma unroll
    for (int o = 32; o > 0; o >>= 1) lsum += __shfl_xor(lsum, o);
    // PV: lane = output dim; V transposed in LDS, float4 per lane
    float acc = 0.f;
    #pragma unroll 7
    for (int jj = 0; jj < 196; jj += 4) {
      float4 pv = *(const float4*)&ps[w][jj];
      float4 vv = *(const float4*)&Vs[lane][jj];
      acc = fmaf(pv.x,vv.x,fmaf(pv.y,vv.y,fmaf(pv.z,vv.z,fmaf(pv.w,vv.w,acc))));
    }
    acc = fmaf(ps[w][196], Vs[lane][196], acc);
    att[(size_t)(b * N_ + n) * D_ + h * HD_ + lane] = f2bf(acc / lsum);
  }
}

// ---------------------------------------------------------------- time attention
__global__ __launch_bounds__(256) void time_attn_kernel(const float* __restrict__ qkv,
                                                        unsigned short* __restrict__ att) {
  int idx = blockIdx.x * 4 + (threadIdx.x >> 6);
  int bh = idx / P_, p = idx % P_;
  int b = bh / H_, h = bh % H_;
  int lane = threadIdx.x & 63;
  const float* base = qkv + (size_t)b * N_ * QKVC_ + h * HD_ + lane;
  float k[9], v[9];
  k[0] = base[D_];
  v[0] = base[2*D_];
  #pragma unroll
  for (int j = 0; j < 8; ++j) {
    size_t r = (size_t)(1 + j * P_ + p) * QKVC_;
    k[j+1] = base[r + D_];
    v[j+1] = base[r + 2*D_];
  }
  #pragma unroll 1
  for (int f = 0; f < F_; ++f) {
    size_t qr = (size_t)(1 + f * P_ + p) * QKVC_;
    float qd = base[qr] * SCALE_;
    float s[9];
    #pragma unroll
    for (int j = 0; j < 9; ++j) {
      float prod = qd * k[j];
      #pragma unroll
      for (int o = 32; o > 0; o >>= 1) prod += __shfl_xor(prod, o);
      s[j] = prod;
    }
    float m = s[0];
    #pragma unroll
    for (int j = 1; j < 9; ++j) m = fmaxf(m, s[j]);
    float den = 0.f, o_ = 0.f;
    #pragma unroll
    for (int j = 0; j < 9; ++j) {
      float pj = __expf(s[j] - m);
      den += pj;
      o_ = fmaf(pj, v[j], o_);
    }
    att[(size_t)(b * N_ + 1 + f * P_ + p) * D_ + h * HD_ + lane] = f2bf(o_ / den);
  }
}

// ---------------------------------------------------------------- launcher
extern "C" void kernel_launch(void* const* d_in, const int* in_sizes, int n_in,
                              void* d_out, int out_size, void* d_ws, size_t ws_size,
                              hipStream_t stream) {
  const float* x_in     = (const float*)d_in[0];
  const float* qkv_w_t  = (const float*)d_in[1];
  const float* proj_w_t = (const float*)d_in[2];
  const float* proj_b_t = (const float*)d_in[3];
  const float* qkv_w_s  = (const float*)d_in[4];
  const float* proj_w_s = (const float*)d_in[5];
  const float* proj_b_s = (const float*)d_in[6];
  const float* fc1_w    = (const float*)d_in[7];
  const float* fc1_b    = (const float*)d_in[8];
  const float* fc2_w    = (const float*)d_in[9];
  const float* fc2_b    = (const float*)d_in[10];
  const float* ln1_g    = (const float*)d_in[11];
  const float* ln1_b    = (const float*)d_in[12];
  const float* ln2_g    = (const float*)d_in[13];
  const float* ln2_b    = (const float*)d_in[14];
  const float* ln3_g    = (const float*)d_in[15];
  const float* ln3_b    = (const float*)d_in[16];

  float* X_out = (float*)d_out;
  char* ws = (char*)d_ws;
  // layout (bytes):
  //   0        : Wbf  bf16 per-layer weights (18,874,368 B)
  //   WQ       : QKV  fp32 [BN,2304] (57,839,616 B)  -- aliased as Hbf bf16 [BN,3072]
  //   WQ+QK    : TR   fp32 [BN,768]  (19,279,872 B)
  //   ...      : Abf  bf16 [BN,768]  ( 9,639,936 B)  -- aliased as ATT
  unsigned short* Wbf = (unsigned short*)ws;
  const size_t WOFF = 18874368;
  float*          QKV = (float*)(ws + WOFF);
  unsigned short* Hbf = (unsigned short*)(ws + WOFF);
  float*          TR  = (float*)(ws + WOFF + 57839616);
  unsigned short* Abf = (unsigned short*)(ws + WOFF + 57839616 + 19279872);

  unsigned short* wqkv_t = Wbf + 0;
  unsigned short* wproj_t= Wbf + 1769472;
  unsigned short* wqkv_s = Wbf + 2359296;
  unsigned short* wproj_s= Wbf + 4128768;
  unsigned short* wfc1   = Wbf + 4718592;
  unsigned short* wfc2   = Wbf + 7077888;

  dim3 blk(256);
  dim3 g_qkv(50, 18), g_proj(50, 6), g_fc1(50, 24), g_fc2(50, 6);

  for (int l = 0; l < L_; ++l) {
    const float* X = (l == 0) ? x_in : (const float*)X_out;
    cvt_layer_kernel<<<2048, blk, 0, stream>>>(
        qkv_w_t + (size_t)l*SQKV, proj_w_t + (size_t)l*SPROJ,
        qkv_w_s + (size_t)l*SQKV, proj_w_s + (size_t)l*SPROJ,
        fc1_w + (size_t)l*SFC, fc2_w + (size_t)l*SFC, Wbf);
    // 1. a = LN3(x)
    ln_kernel<<<BN_, blk, 0, stream>>>(X, ln3_g + l*D_, ln3_b + l*D_, Abf);
    // 2. qkv_t
    mfma_gemm<0><<<g_qkv, blk, 0, stream>>>(Abf, wqkv_t, nullptr, nullptr, QKV, BN_, QKVC_, D_);
    // 3/4. time attention (+ cls)
    cls_attn_kernel<<<B_*H_, blk, 0, stream>>>(QKV, Abf);
    time_attn_kernel<<<(B_*H_*P_)/4, blk, 0, stream>>>(QKV, Abf);
    // 5. time_residual = x + att @ proj_w_t^T + b
    mfma_gemm<1><<<g_proj, blk, 0, stream>>>(Abf, wproj_t, proj_b_t + l*D_, X, TR, BN_, D_, D_);
    // 6. a = LN1(time_residual)
    ln_kernel<<<BN_, blk, 0, stream>>>(TR, ln1_g + l*D_, ln1_b + l*D_, Abf);
    // 7. qkv_s
    mfma_gemm<0><<<g_qkv, blk, 0, stream>>>(Abf, wqkv_s, nullptr, nullptr, QKV, BN_, QKVC_, D_);
    // 8/9. space attention (+ cls)
    cls_attn_kernel<<<B_*H_, blk, 0, stream>>>(QKV, Abf);
    space_attn_kernel<<<B_*H_*F_*2, dim3(512), 0, stream>>>(QKV, Abf);
    // 10. space_residual = x + att @ proj_w_s^T + b
    mfma_gemm<1><<<g_proj, blk, 0, stream>>>(Abf, wproj_s, proj_b_s + l*D_, X, TR, BN_, D_, D_);
    // 11. a = LN2(space_residual)
    ln_kernel<<<BN_, blk, 0, stream>>>(TR, ln2_g + l*D_, ln2_b + l*D_, Abf);
    // 12. h = gelu(a @ fc1^T + b)  (bf16 out, into QKV region)
    mfma_gemm<2><<<g_fc1, blk, 0, stream>>>(Abf, wfc1, fc1_b + l*MLP_, nullptr, Hbf, BN_, MLP_, D_);
    // 13. out = space_residual + h @ fc2^T + b
    mfma_gemm<1><<<g_fc2, blk, 0, stream>>>(Hbf, wfc2, fc2_b + l*D_, TR, X_out, BN_, D_, MLP_);
  }
}

// Round 3
// 2723.858 us; speedup vs baseline: 3.7011x; 1.3366x over previous
//
#include <hip/hip_runtime.h>
#include <cmath>

#define B_ 4
#define F_ 8
#define P_ 196
#define D_ 768
#define H_ 12
#define HD_ 64
#define L_ 4
#define MLP_ 3072
#define N_ (1 + F_*P_)     // 1569
#define BN_ (B_*N_)        // 6276
#define SCALE_ 0.125f
#define QKVC_ (3*D_)       // 2304

typedef __bf16 bf16x8 __attribute__((ext_vector_type(8)));
typedef float f32x4 __attribute__((ext_vector_type(4)));
typedef const __attribute__((address_space(1))) void* gas_ptr;
typedef __attribute__((address_space(3))) void* las_ptr;

__device__ __forceinline__ unsigned short f2bf(float f) {
  union { __bf16 b; unsigned short u; } cv;
  cv.b = (__bf16)f;
  return cv.u;
}
__device__ __forceinline__ float bf2f(unsigned short u) {
  union { float f; unsigned int i; } cv; cv.i = ((unsigned int)u) << 16; return cv.f;
}
__device__ __forceinline__ unsigned int pk2(float a, float b) {
  return (unsigned int)f2bf(a) | ((unsigned int)f2bf(b) << 16);
}

__device__ __forceinline__ float gelu_exact(float x) {
  return 0.5f * x * (1.0f + erff(x * 0.70710678118654752f));
}

// ---------------------------------------------------------------- weight convert (per layer)
#define SQKV 1769472
#define SPROJ 589824
#define SFC 2359296

__device__ __forceinline__ void cvt_seg(const float* __restrict__ src,
                                        unsigned short* __restrict__ dst,
                                        int n, int t0, int stride) {
  for (int i = t0; i < (n >> 2); i += stride) {
    float4 v = ((const float4*)src)[i];
    ushort4 o;
    o.x = f2bf(v.x); o.y = f2bf(v.y); o.z = f2bf(v.z); o.w = f2bf(v.w);
    ((ushort4*)dst)[i] = o;
  }
}

__global__ __launch_bounds__(256) void cvt_layer_kernel(const float* qt, const float* pt,
                                                        const float* qs, const float* ps,
                                                        const float* f1, const float* f2,
                                                        unsigned short* wb) {
  int t0 = blockIdx.x * blockDim.x + threadIdx.x;
  int stride = gridDim.x * blockDim.x;
  cvt_seg(qt, wb + 0,       SQKV,  t0, stride);
  cvt_seg(pt, wb + 1769472, SPROJ, t0, stride);
  cvt_seg(qs, wb + 2359296, SQKV,  t0, stride);
  cvt_seg(ps, wb + 4128768, SPROJ, t0, stride);
  cvt_seg(f1, wb + 4718592, SFC,   t0, stride);
  cvt_seg(f2, wb + 7077888, SFC,   t0, stride);
}

// ---------------------------------------------------------------- LayerNorm (fp32 in, bf16 out)
__global__ __launch_bounds__(256) void ln_kernel(const float* __restrict__ x,
                                                 const float* __restrict__ g,
                                                 const float* __restrict__ b,
                                                 unsigned short* __restrict__ out) {
  int row = blockIdx.x;
  const float* xr = x + (size_t)row * D_;
  unsigned short* orow = out + (size_t)row * D_;
  int tid = threadIdx.x;
  float v0 = xr[tid], v1 = xr[tid + 256], v2 = xr[tid + 512];
  float s  = v0 + v1 + v2;
  float ss = v0*v0 + v1*v1 + v2*v2;
  #pragma unroll
  for (int o = 32; o > 0; o >>= 1) { s += __shfl_xor(s, o); ss += __shfl_xor(ss, o); }
  __shared__ float sm[8];
  int w = tid >> 6;
  if ((tid & 63) == 0) { sm[w*2] = s; sm[w*2+1] = ss; }
  __syncthreads();
  float tot  = sm[0] + sm[2] + sm[4] + sm[6];
  float tot2 = sm[1] + sm[3] + sm[5] + sm[7];
  float mean = tot * (1.0f/D_);
  float var  = tot2 * (1.0f/D_) - mean*mean;
  float rs   = rsqrtf(var + 1e-5f);
  orow[tid]       = f2bf((v0 - mean)*rs*g[tid]       + b[tid]);
  orow[tid + 256] = f2bf((v1 - mean)*rs*g[tid + 256] + b[tid + 256]);
  orow[tid + 512] = f2bf((v2 - mean)*rs*g[tid + 512] + b[tid + 512]);
}

// ---------------------------------------------------------------- MFMA GEMM
// C[M,NN] = A[M,K](bf16) @ W[NN,K](bf16)^T, fp32 accumulate.
// EPI 0: fp32 out. EPI 1: +bias+Res fp32 out. EPI 2: gelu(+bias) bf16 out. EPI 3: bf16 out.
template<int EPI>
__global__ __launch_bounds__(256) void mfma_gemm(const unsigned short* __restrict__ A,
                                                 const unsigned short* __restrict__ W,
                                                 const float* __restrict__ bias,
                                                 const float* __restrict__ Res,
                                                 void* __restrict__ Cout,
                                                 int M, int NN, int K) {
  __shared__ __align__(16) unsigned short As[128*32];
  __shared__ __align__(16) unsigned short Bs[128*32];
  int tid = threadIdx.x;
  int w = tid >> 6, l = tid & 63;
  int m0 = blockIdx.x * 128, n0 = blockIdx.y * 128;
  int wr = w >> 1, wc = w & 1;

  int c0 = tid, c1 = tid + 256;
  int rA0 = c0 >> 2, kA0 = (c0 & 3) << 3;
  int rA1 = c1 >> 2, kA1 = (c1 & 3) << 3;
  int mr0 = m0 + rA0; if (mr0 >= M) mr0 = M - 1;
  int mr1 = m0 + rA1; if (mr1 >= M) mr1 = M - 1;
  const unsigned short* gA0 = A + (size_t)mr0 * K + kA0;
  const unsigned short* gA1 = A + (size_t)mr1 * K + kA1;
  const unsigned short* gB0 = W + (size_t)(n0 + rA0) * K + kA0;
  const unsigned short* gB1 = W + (size_t)(n0 + rA1) * K + kA1;
  unsigned short* lA0 = &As[(size_t)(w*64)*8];
  unsigned short* lA1 = &As[(size_t)(256 + w*64)*8];
  unsigned short* lB0 = &Bs[(size_t)(w*64)*8];
  unsigned short* lB1 = &Bs[(size_t)(256 + w*64)*8];

  int fr = l & 15, fq = l >> 4;
  f32x4 acc[4][4] = {};

  for (int k0 = 0; k0 < K; k0 += 32) {
    __builtin_amdgcn_global_load_lds((gas_ptr)(gA0 + k0), (las_ptr)lA0, 16, 0, 0);
    __builtin_amdgcn_global_load_lds((gas_ptr)(gA1 + k0), (las_ptr)lA1, 16, 0, 0);
    __builtin_amdgcn_global_load_lds((gas_ptr)(gB0 + k0), (las_ptr)lB0, 16, 0, 0);
    __builtin_amdgcn_global_load_lds((gas_ptr)(gB1 + k0), (las_ptr)lB1, 16, 0, 0);
    __syncthreads();
    bf16x8 af[4], bf[4];
    #pragma unroll
    for (int i = 0; i < 4; ++i)
      af[i] = *(const bf16x8*)&As[(wr*64 + i*16 + fr)*32 + fq*8];
    #pragma unroll
    for (int j = 0; j < 4; ++j)
      bf[j] = *(const bf16x8*)&Bs[(wc*64 + j*16 + fr)*32 + fq*8];
    #pragma unroll
    for (int i = 0; i < 4; ++i)
      #pragma unroll
      for (int j = 0; j < 4; ++j)
        acc[i][j] = __builtin_amdgcn_mfma_f32_16x16x32_bf16(af[i], bf[j], acc[i][j], 0, 0, 0);
    __syncthreads();
  }

  #pragma unroll
  for (int j = 0; j < 4; ++j) {
    int col = n0 + wc*64 + j*16 + fr;
    float bj = (EPI == 1 || EPI == 2) ? bias[col] : 0.f;
    #pragma unroll
    for (int i = 0; i < 4; ++i) {
      int rowb = m0 + wr*64 + i*16 + fq*4;
      #pragma unroll
      for (int r = 0; r < 4; ++r) {
        int row = rowb + r;
        if (row < M) {
          float v = acc[i][j][r] + bj;
          if (EPI == 1) v += Res[(size_t)row * NN + col];
          if (EPI == 2) {
            ((unsigned short*)Cout)[(size_t)row * NN + col] = f2bf(gelu_exact(v));
          } else if (EPI == 3) {
            ((unsigned short*)Cout)[(size_t)row * NN + col] = f2bf(v);
          } else {
            ((float*)Cout)[(size_t)row * NN + col] = v;
          }
        }
      }
    }
  }
}

// ---------------------------------------------------------------- cls attention (bf16 qkv)
__global__ __launch_bounds__(256) void cls_attn_kernel(const unsigned short* __restrict__ qkv,
                                                       unsigned short* __restrict__ att) {
  int bh = blockIdx.x;
  int b = bh / H_, h = bh % H_;
  const unsigned short* base = qkv + (size_t)b * N_ * QKVC_ + h * HD_;
  __shared__ float q[HD_];
  __shared__ float s[N_];
  __shared__ float red[8];
  __shared__ float pv[4][HD_];
  int tid = threadIdx.x;
  if (tid < HD_) q[tid] = bf2f(base[tid]) * SCALE_;
  __syncthreads();
  float lmax = -1e30f;
  for (int j = tid; j < N_; j += 256) {
    const unsigned short* kp = base + (size_t)j * QKVC_ + D_;
    float acc = 0.f;
    #pragma unroll
    for (int c = 0; c < 8; ++c) {
      uint4 kv = *(const uint4*)(kp + c*8);
      const unsigned short* e = (const unsigned short*)&kv;
      #pragma unroll
      for (int t = 0; t < 8; ++t) acc = fmaf(q[c*8+t], bf2f(e[t]), acc);
    }
    s[j] = acc;
    lmax = fmaxf(lmax, acc);
  }
  #pragma unroll
  for (int o = 32; o > 0; o >>= 1) lmax = fmaxf(lmax, __shfl_xor(lmax, o));
  if ((tid & 63) == 0) red[tid >> 6] = lmax;
  __syncthreads();
  float m = fmaxf(fmaxf(red[0], red[1]), fmaxf(red[2], red[3]));
  float lsum = 0.f;
  for (int j = tid; j < N_; j += 256) { float p = __expf(s[j] - m); s[j] = p; lsum += p; }
  #pragma unroll
  for (int o = 32; o > 0; o >>= 1) lsum += __shfl_xor(lsum, o);
  if ((tid & 63) == 0) red[4 + (tid >> 6)] = lsum;
  __syncthreads();
  float denom = red[4] + red[5] + red[6] + red[7];
  int d = tid & 63, gidx = tid >> 6;
  float acc = 0.f;
  for (int j = gidx; j < N_; j += 4)
    acc += s[j] * bf2f(base[(size_t)j * QKVC_ + 2*D_ + d]);
  pv[gidx][d] = acc;
  __syncthreads();
  if (gidx == 0) {
    att[(size_t)(b * N_) * D_ + h * HD_ + d] = f2bf((pv[0][d] + pv[1][d] + pv[2][d] + pv[3][d]) / denom);
  }
}

// ---------------------------------------------------------------- space attention (MFMA)
// One block per (bh,f). 4 waves; wave handles 16-query tiles qt = w, w+4, ...
// S^T = K·Q^T (mfma A=K rows j, B=Q rows q) -> softmax over j (per-lane + 2 shfl)
// O^T = Vt·P (mfma A=Vt rows d, B=P rows q) -> packed 8B global writes.
__global__ __launch_bounds__(256) void space_attn_mfma(const unsigned short* __restrict__ qkv,
                                                       unsigned short* __restrict__ att) {
  int blk = blockIdx.x;
  int f = blk % F_; int bh = blk / F_;
  int b = bh / H_, h = bh % H_;
  const unsigned short* qbase = qkv + (size_t)b * N_ * QKVC_ + h * HD_;
  __shared__ __align__(16) unsigned short Ksm[208*64];   // [j][d] rows 128B, swizzled
  __shared__ __align__(16) unsigned short Vtm[64*256];   // [d][j] rows 512B, swizzled
  __shared__ __align__(16) unsigned short Pm[4*16*256];  // per-wave [q][j] rows 512B, swizzled
  int tid = threadIdx.x;

  // stage K (rows >=197 zero)
  for (int c = tid; c < 208*8; c += 256) {
    int j = c >> 3, cb = (c & 7) * 16;
    uint4 val = make_uint4(0,0,0,0);
    if (j < 197) {
      int n = (j == 0) ? 0 : (1 + f*P_ + j - 1);
      val = *(const uint4*)(qbase + (size_t)n*QKVC_ + D_ + cb/2);
    }
    *(uint4*)((char*)Ksm + j*128 + (cb ^ ((j&7)<<4))) = val;
  }
  // stage Vt transposed (j cols >=197 zero, cover to j<224)
  for (int c = tid; c < 112*8; c += 256) {
    int jj = c % 112, dc = c / 112;
    int j0 = jj * 2;
    uint4 r0 = make_uint4(0,0,0,0), r1 = make_uint4(0,0,0,0);
    if (j0 < 197) {
      int n = (j0 == 0) ? 0 : (1 + f*P_ + j0 - 1);
      r0 = *(const uint4*)(qbase + (size_t)n*QKVC_ + 2*D_ + dc*8);
    }
    if (j0 + 1 < 197) {
      int n = 1 + f*P_ + j0;   // token for key j0+1
      r1 = *(const uint4*)(qbase + (size_t)n*QKVC_ + 2*D_ + dc*8);
    }
    const unsigned short* e0 = (const unsigned short*)&r0;
    const unsigned short* e1 = (const unsigned short*)&r1;
    #pragma unroll
    for (int e = 0; e < 8; ++e) {
      int d = dc*8 + e;
      unsigned int pk = (unsigned int)e0[e] | ((unsigned int)e1[e] << 16);
      *(unsigned int*)((char*)Vtm + d*512 + ((2*j0) ^ ((d&7)<<4))) = pk;
    }
  }
  int w = tid >> 6, l = tid & 63;
  int fr = l & 15, fq = l >> 4;
  char* Pw = (char*)Pm + w * 8192;
  // zero P pad cols [208,224)
  {
    int q = l >> 2, cb = 416 + (l & 3) * 8;
    *(unsigned long long*)(Pw + q*512 + (cb ^ ((q&7)<<4))) = 0ull;
  }
  __syncthreads();

  int swz = (fr & 7) << 4;
  for (int qt = w; qt <= 12; qt += 4) {
    int qrow = qt*16 + fr; if (qrow > 195) qrow = 195;
    int n_q = 1 + f*P_ + qrow;
    bf16x8 qf0 = *(const bf16x8*)(qbase + (size_t)n_q*QKVC_ + fq*8);
    bf16x8 qf1 = *(const bf16x8*)(qbase + (size_t)n_q*QKVC_ + 32 + fq*8);
    f32x4 s[13];
    #pragma unroll
    for (int jt = 0; jt < 13; ++jt) s[jt] = (f32x4){0.f,0.f,0.f,0.f};
    #pragma unroll
    for (int jt = 0; jt < 13; ++jt) {
      bf16x8 a0 = *(const bf16x8*)((char*)Ksm + (jt*16+fr)*128 + ((fq*16) ^ swz));
      s[jt] = __builtin_amdgcn_mfma_f32_16x16x32_bf16(a0, qf0, s[jt], 0, 0, 0);
      bf16x8 a1 = *(const bf16x8*)((char*)Ksm + (jt*16+fr)*128 + ((64 + fq*16) ^ swz));
      s[jt] = __builtin_amdgcn_mfma_f32_16x16x32_bf16(a1, qf1, s[jt], 0, 0, 0);
    }
    // softmax over j for col q=fr (lane holds j = jt*16 + fq*4 + r)
    float m = -1e30f;
    #pragma unroll
    for (int jt = 0; jt < 13; ++jt) {
      #pragma unroll
      for (int r = 0; r < 4; ++r) {
        if (jt*16 + fq*4 + r < 197) m = fmaxf(m, s[jt][r]);
      }
    }
    m = fmaxf(m, __shfl_xor(m, 16));
    m = fmaxf(m, __shfl_xor(m, 32));
    float den = 0.f;
    #pragma unroll
    for (int jt = 0; jt < 13; ++jt) {
      #pragma unroll
      for (int r = 0; r < 4; ++r) {
        float p = (jt*16 + fq*4 + r < 197) ? __expf((s[jt][r] - m) * SCALE_) : 0.f;
        s[jt][r] = p;
        den += p;
      }
    }
    den += __shfl_xor(den, 16);
    den += __shfl_xor(den, 32);
    // write P[q=fr][j] packed 4x bf16 (8B)
    #pragma unroll
    for (int jt = 0; jt < 13; ++jt) {
      unsigned long long pv = (unsigned long long)pk2(s[jt][0], s[jt][1])
                            | ((unsigned long long)pk2(s[jt][2], s[jt][3]) << 32);
      *(unsigned long long*)(Pw + fr*512 + ((jt*32 + fq*8) ^ swz)) = pv;
    }
    // PV: O^T[d][q]
    float rden = 1.0f / den;
    bool wr_ok = (qt*16 + fr) < 196;
    int n_out = 1 + f*P_ + qt*16 + fr;
    #pragma unroll
    for (int dt = 0; dt < 4; ++dt) {
      f32x4 o = (f32x4){0.f,0.f,0.f,0.f};
      #pragma unroll
      for (int ks = 0; ks < 7; ++ks) {
        bf16x8 av = *(const bf16x8*)((char*)Vtm + (dt*16+fr)*512 + ((ks*64 + fq*16) ^ swz));
        bf16x8 bp = *(const bf16x8*)(Pw + fr*512 + ((ks*64 + fq*16) ^ swz));
        o = __builtin_amdgcn_mfma_f32_16x16x32_bf16(av, bp, o, 0, 0, 0);
      }
      if (wr_ok) {
        unsigned long long ov = (unsigned long long)pk2(o[0]*rden, o[1]*rden)
                              | ((unsigned long long)pk2(o[2]*rden, o[3]*rden) << 32);
        *(unsigned long long*)(att + (size_t)(b*N_ + n_out)*D_ + h*HD_ + dt*16 + fq*4) = ov;
      }
    }
  }
}

// ---------------------------------------------------------------- time attention (bf16 qkv)
__global__ __launch_bounds__(256) void time_attn_kernel(const unsigned short* __restrict__ qkv,
                                                        unsigned short* __restrict__ att) {
  int idx = blockIdx.x * 4 + (threadIdx.x >> 6);
  int bh = idx / P_, p = idx % P_;
  int b = bh / H_, h = bh % H_;
  int lane = threadIdx.x & 63;
  const unsigned short* base = qkv + (size_t)b * N_ * QKVC_ + h * HD_ + lane;
  float k[9], v[9];
  k[0] = bf2f(base[D_]);
  v[0] = bf2f(base[2*D_]);
  #pragma unroll
  for (int j = 0; j < 8; ++j) {
    size_t r = (size_t)(1 + j * P_ + p) * QKVC_;
    k[j+1] = bf2f(base[r + D_]);
    v[j+1] = bf2f(base[r + 2*D_]);
  }
  #pragma unroll 1
  for (int f = 0; f < F_; ++f) {
    size_t qr = (size_t)(1 + f * P_ + p) * QKVC_;
    float qd = bf2f(base[qr]) * SCALE_;
    float s[9];
    #pragma unroll
    for (int j = 0; j < 9; ++j) {
      float prod = qd * k[j];
      #pragma unroll
      for (int o = 32; o > 0; o >>= 1) prod += __shfl_xor(prod, o);
      s[j] = prod;
    }
    float m = s[0];
    #pragma unroll
    for (int j = 1; j < 9; ++j) m = fmaxf(m, s[j]);
    float den = 0.f, o_ = 0.f;
    #pragma unroll
    for (int j = 0; j < 9; ++j) {
      float pj = __expf(s[j] - m);
      den += pj;
      o_ = fmaf(pj, v[j], o_);
    }
    att[(size_t)(b * N_ + 1 + f * P_ + p) * D_ + h * HD_ + lane] = f2bf(o_ / den);
  }
}

// ---------------------------------------------------------------- launcher
extern "C" void kernel_launch(void* const* d_in, const int* in_sizes, int n_in,
                              void* d_out, int out_size, void* d_ws, size_t ws_size,
                              hipStream_t stream) {
  const float* x_in     = (const float*)d_in[0];
  const float* qkv_w_t  = (const float*)d_in[1];
  const float* proj_w_t = (const float*)d_in[2];
  const float* proj_b_t = (const float*)d_in[3];
  const float* qkv_w_s  = (const float*)d_in[4];
  const float* proj_w_s = (const float*)d_in[5];
  const float* proj_b_s = (const float*)d_in[6];
  const float* fc1_w    = (const float*)d_in[7];
  const float* fc1_b    = (const float*)d_in[8];
  const float* fc2_w    = (const float*)d_in[9];
  const float* fc2_b    = (const float*)d_in[10];
  const float* ln1_g    = (const float*)d_in[11];
  const float* ln1_b    = (const float*)d_in[12];
  const float* ln2_g    = (const float*)d_in[13];
  const float* ln2_b    = (const float*)d_in[14];
  const float* ln3_g    = (const float*)d_in[15];
  const float* ln3_b    = (const float*)d_in[16];

  float* X_out = (float*)d_out;
  char* ws = (char*)d_ws;
  unsigned short* Wbf = (unsigned short*)ws;
  const size_t WOFF = 18874368;
  unsigned short* QKVbf = (unsigned short*)(ws + WOFF);          // [BN,2304] bf16
  unsigned short* Hbf   = (unsigned short*)(ws + WOFF);          // [BN,3072] bf16 (aliased)
  float*          TR    = (float*)(ws + WOFF + 57839616);
  unsigned short* Abf   = (unsigned short*)(ws + WOFF + 57839616 + 19279872);

  unsigned short* wqkv_t = Wbf + 0;
  unsigned short* wproj_t= Wbf + 1769472;
  unsigned short* wqkv_s = Wbf + 2359296;
  unsigned short* wproj_s= Wbf + 4128768;
  unsigned short* wfc1   = Wbf + 4718592;
  unsigned short* wfc2   = Wbf + 7077888;

  dim3 blk(256);
  dim3 g_qkv(50, 18), g_proj(50, 6), g_fc1(50, 24), g_fc2(50, 6);

  for (int l = 0; l < L_; ++l) {
    const float* X = (l == 0) ? x_in : (const float*)X_out;
    cvt_layer_kernel<<<2048, blk, 0, stream>>>(
        qkv_w_t + (size_t)l*SQKV, proj_w_t + (size_t)l*SPROJ,
        qkv_w_s + (size_t)l*SQKV, proj_w_s + (size_t)l*SPROJ,
        fc1_w + (size_t)l*SFC, fc2_w + (size_t)l*SFC, Wbf);
    // 1. a = LN3(x)
    ln_kernel<<<BN_, blk, 0, stream>>>(X, ln3_g + l*D_, ln3_b + l*D_, Abf);
    // 2. qkv_t (bf16 out)
    mfma_gemm<3><<<g_qkv, blk, 0, stream>>>(Abf, wqkv_t, nullptr, nullptr, QKVbf, BN_, QKVC_, D_);
    // 3/4. time attention (+ cls)
    cls_attn_kernel<<<B_*H_, blk, 0, stream>>>(QKVbf, Abf);
    time_attn_kernel<<<(B_*H_*P_)/4, blk, 0, stream>>>(QKVbf, Abf);
    // 5. time_residual = x + att @ proj_w_t^T + b
    mfma_gemm<1><<<g_proj, blk, 0, stream>>>(Abf, wproj_t, proj_b_t + l*D_, X, TR, BN_, D_, D_);
    // 6. a = LN1(time_residual)
    ln_kernel<<<BN_, blk, 0, stream>>>(TR, ln1_g + l*D_, ln1_b + l*D_, Abf);
    // 7. qkv_s (bf16 out)
    mfma_gemm<3><<<g_qkv, blk, 0, stream>>>(Abf, wqkv_s, nullptr, nullptr, QKVbf, BN_, QKVC_, D_);
    // 8/9. space attention (+ cls)
    cls_attn_kernel<<<B_*H_, blk, 0, stream>>>(QKVbf, Abf);
    space_attn_mfma<<<B_*H_*F_, blk, 0, stream>>>(QKVbf, Abf);
    // 10. space_residual = x + att @ proj_w_s^T + b
    mfma_gemm<1><<<g_proj, blk, 0, stream>>>(Abf, wproj_s, proj_b_s + l*D_, X, TR, BN_, D_, D_);
    // 11. a = LN2(space_residual)
    ln_kernel<<<BN_, blk, 0, stream>>>(TR, ln2_g + l*D_, ln2_b + l*D_, Abf);
    // 12. h = gelu(a @ fc1^T + b)  (bf16 out)
    mfma_gemm<2><<<g_fc1, blk, 0, stream>>>(Abf, wfc1, fc1_b + l*MLP_, nullptr, Hbf, BN_, MLP_, D_);
    // 13. out = space_residual + h @ fc2^T + b
    mfma_gemm<1><<<g_fc2, blk, 0, stream>>>(Hbf, wfc2, fc2_b + l*D_, TR, X_out, BN_, D_, MLP_);
  }
}

// Round 4
// 1976.910 us; speedup vs baseline: 5.0995x; 1.3778x over previous
//
#include <hip/hip_runtime.h>
#include <cmath>

#define B_ 4
#define F_ 8
#define P_ 196
#define D_ 768
#define H_ 12
#define HD_ 64
#define L_ 4
#define MLP_ 3072
#define N_ (1 + F_*P_)     // 1569
#define BN_ (B_*N_)        // 6276
#define SCALE_ 0.125f
#define QKVC_ (3*D_)       // 2304

typedef __bf16 bf16x8 __attribute__((ext_vector_type(8)));
typedef float f32x4 __attribute__((ext_vector_type(4)));
typedef const __attribute__((address_space(1))) void* gas_ptr;
typedef __attribute__((address_space(3))) void* las_ptr;

__device__ __forceinline__ unsigned short f2bf(float f) {
  union { __bf16 b; unsigned short u; } cv;
  cv.b = (__bf16)f;
  return cv.u;
}
__device__ __forceinline__ float bf2f(unsigned short u) {
  union { float f; unsigned int i; } cv; cv.i = ((unsigned int)u) << 16; return cv.f;
}
__device__ __forceinline__ unsigned int pk2(float a, float b) {
  return (unsigned int)f2bf(a) | ((unsigned int)f2bf(b) << 16);
}

__device__ __forceinline__ float gelu_exact(float x) {
  return 0.5f * x * (1.0f + erff(x * 0.70710678118654752f));
}

// ---------------------------------------------------------------- weight convert (per layer)
#define SQKV 1769472
#define SPROJ 589824
#define SFC 2359296

__device__ __forceinline__ void cvt_seg(const float* __restrict__ src,
                                        unsigned short* __restrict__ dst,
                                        int n, int t0, int stride) {
  for (int i = t0; i < (n >> 2); i += stride) {
    float4 v = ((const float4*)src)[i];
    ushort4 o;
    o.x = f2bf(v.x); o.y = f2bf(v.y); o.z = f2bf(v.z); o.w = f2bf(v.w);
    ((ushort4*)dst)[i] = o;
  }
}

__global__ __launch_bounds__(256) void cvt_layer_kernel(const float* qt, const float* pt,
                                                        const float* qs, const float* ps,
                                                        const float* f1, const float* f2,
                                                        unsigned short* wb) {
  int t0 = blockIdx.x * blockDim.x + threadIdx.x;
  int stride = gridDim.x * blockDim.x;
  cvt_seg(qt, wb + 0,       SQKV,  t0, stride);
  cvt_seg(pt, wb + 1769472, SPROJ, t0, stride);
  cvt_seg(qs, wb + 2359296, SQKV,  t0, stride);
  cvt_seg(ps, wb + 4128768, SPROJ, t0, stride);
  cvt_seg(f1, wb + 4718592, SFC,   t0, stride);
  cvt_seg(f2, wb + 7077888, SFC,   t0, stride);
}

// ---------------------------------------------------------------- LayerNorm (fp32 in, bf16 out)
__global__ __launch_bounds__(256) void ln_kernel(const float* __restrict__ x,
                                                 const float* __restrict__ g,
                                                 const float* __restrict__ b,
                                                 unsigned short* __restrict__ out) {
  int row = blockIdx.x;
  const float* xr = x + (size_t)row * D_;
  unsigned short* orow = out + (size_t)row * D_;
  int tid = threadIdx.x;
  float v0 = xr[tid], v1 = xr[tid + 256], v2 = xr[tid + 512];
  float s  = v0 + v1 + v2;
  float ss = v0*v0 + v1*v1 + v2*v2;
  #pragma unroll
  for (int o = 32; o > 0; o >>= 1) { s += __shfl_xor(s, o); ss += __shfl_xor(ss, o); }
  __shared__ float sm[8];
  int w = tid >> 6;
  if ((tid & 63) == 0) { sm[w*2] = s; sm[w*2+1] = ss; }
  __syncthreads();
  float tot  = sm[0] + sm[2] + sm[4] + sm[6];
  float tot2 = sm[1] + sm[3] + sm[5] + sm[7];
  float mean = tot * (1.0f/D_);
  float var  = tot2 * (1.0f/D_) - mean*mean;
  float rs   = rsqrtf(var + 1e-5f);
  orow[tid]       = f2bf((v0 - mean)*rs*g[tid]       + b[tid]);
  orow[tid + 256] = f2bf((v1 - mean)*rs*g[tid + 256] + b[tid + 256]);
  orow[tid + 512] = f2bf((v2 - mean)*rs*g[tid + 512] + b[tid + 512]);
}

// ---------------------------------------------------------------- MFMA GEMM (double-buffered)
// C[M,NN] = A[M,K](bf16) @ W[NN,K](bf16)^T, fp32 accumulate.
// EPI 0: fp32 out. EPI 1: +bias+Res fp32 out. EPI 2: gelu(+bias) bf16 out. EPI 3: bf16 out.
template<int EPI>
__global__ __launch_bounds__(256) void mfma_gemm(const unsigned short* __restrict__ A,
                                                 const unsigned short* __restrict__ W,
                                                 const float* __restrict__ bias,
                                                 const float* __restrict__ Res,
                                                 void* __restrict__ Cout,
                                                 int M, int NN, int K) {
  __shared__ __align__(16) unsigned short As[2][128*32];
  __shared__ __align__(16) unsigned short Bs[2][128*32];
  int tid = threadIdx.x;
  int w = tid >> 6, l = tid & 63;
  int m0 = blockIdx.x * 128, n0 = blockIdx.y * 128;
  int wr = w >> 1, wc = w & 1;

  int c0 = tid, c1 = tid + 256;
  int rA0 = c0 >> 2, kA0 = (c0 & 3) << 3;
  int rA1 = c1 >> 2, kA1 = (c1 & 3) << 3;
  int mr0 = m0 + rA0; if (mr0 >= M) mr0 = M - 1;
  int mr1 = m0 + rA1; if (mr1 >= M) mr1 = M - 1;
  const unsigned short* gA0 = A + (size_t)mr0 * K + kA0;
  const unsigned short* gA1 = A + (size_t)mr1 * K + kA1;
  const unsigned short* gB0 = W + (size_t)(n0 + rA0) * K + kA0;
  const unsigned short* gB1 = W + (size_t)(n0 + rA1) * K + kA1;
  // wave-uniform LDS bases (global_load_lds: base + lane*16)
  int wb0 = w * 512, wb1 = 2048 + w * 512;

  int fr = l & 15, fq = l >> 4;
  f32x4 acc[4][4] = {};

#define STAGE(k0, buf) do { \
    __builtin_amdgcn_global_load_lds((gas_ptr)(gA0 + (k0)), (las_ptr)&As[buf][wb0], 16, 0, 0); \
    __builtin_amdgcn_global_load_lds((gas_ptr)(gA1 + (k0)), (las_ptr)&As[buf][wb1], 16, 0, 0); \
    __builtin_amdgcn_global_load_lds((gas_ptr)(gB0 + (k0)), (las_ptr)&Bs[buf][wb0], 16, 0, 0); \
    __builtin_amdgcn_global_load_lds((gas_ptr)(gB1 + (k0)), (las_ptr)&Bs[buf][wb1], 16, 0, 0); \
  } while (0)

  STAGE(0, 0);
  __syncthreads();
  int cur = 0;
  for (int k0 = 0; k0 < K; k0 += 32) {
    if (k0 + 32 < K) STAGE(k0 + 32, cur ^ 1);
    bf16x8 af[4], bfr[4];
    #pragma unroll
    for (int i = 0; i < 4; ++i)
      af[i] = *(const bf16x8*)&As[cur][(wr*64 + i*16 + fr)*32 + fq*8];
    #pragma unroll
    for (int j = 0; j < 4; ++j)
      bfr[j] = *(const bf16x8*)&Bs[cur][(wc*64 + j*16 + fr)*32 + fq*8];
    #pragma unroll
    for (int i = 0; i < 4; ++i)
      #pragma unroll
      for (int j = 0; j < 4; ++j)
        acc[i][j] = __builtin_amdgcn_mfma_f32_16x16x32_bf16(af[i], bfr[j], acc[i][j], 0, 0, 0);
    __syncthreads();
    cur ^= 1;
  }
#undef STAGE

  #pragma unroll
  for (int j = 0; j < 4; ++j) {
    int col = n0 + wc*64 + j*16 + fr;
    float bj = (EPI == 1 || EPI == 2) ? bias[col] : 0.f;
    #pragma unroll
    for (int i = 0; i < 4; ++i) {
      int rowb = m0 + wr*64 + i*16 + fq*4;
      #pragma unroll
      for (int r = 0; r < 4; ++r) {
        int row = rowb + r;
        if (row < M) {
          float v = acc[i][j][r] + bj;
          if (EPI == 1) v += Res[(size_t)row * NN + col];
          if (EPI == 2) {
            ((unsigned short*)Cout)[(size_t)row * NN + col] = f2bf(gelu_exact(v));
          } else if (EPI == 3) {
            ((unsigned short*)Cout)[(size_t)row * NN + col] = f2bf(v);
          } else {
            ((float*)Cout)[(size_t)row * NN + col] = v;
          }
        }
      }
    }
  }
}

// ---------------------------------------------------------------- cls attention (split-K)
#define CLS_CH 7
#define CLS_CHSZ 256
// partial layout per (bh,c): [0]=m, [1]=den, [2..65]=pv
__global__ __launch_bounds__(256) void cls_attn_part(const unsigned short* __restrict__ qkv,
                                                     float* __restrict__ part) {
  int blk = blockIdx.x;
  int c = blk % CLS_CH, bh = blk / CLS_CH;
  int b = bh / H_, h = bh % H_;
  const unsigned short* base = qkv + (size_t)b * N_ * QKVC_ + h * HD_;
  __shared__ float q[HD_];
  __shared__ float s[CLS_CHSZ];
  __shared__ float redm[4], redd[4];
  __shared__ float pvs[4][HD_];
  int tid = threadIdx.x;
  if (tid < HD_) q[tid] = bf2f(base[tid]) * SCALE_;
  __syncthreads();
  int j = c * CLS_CHSZ + tid;
  float sc = -1e30f;
  if (j < N_) {
    const unsigned short* kp = base + (size_t)j * QKVC_ + D_;
    float acc = 0.f;
    #pragma unroll
    for (int cc = 0; cc < 8; ++cc) {
      uint4 kv = *(const uint4*)(kp + cc*8);
      const unsigned short* e = (const unsigned short*)&kv;
      #pragma unroll
      for (int t = 0; t < 8; ++t) acc = fmaf(q[cc*8+t], bf2f(e[t]), acc);
    }
    sc = acc;
  }
  float m = sc;
  #pragma unroll
  for (int o = 32; o > 0; o >>= 1) m = fmaxf(m, __shfl_xor(m, o));
  if ((tid & 63) == 0) redm[tid >> 6] = m;
  __syncthreads();
  m = fmaxf(fmaxf(redm[0], redm[1]), fmaxf(redm[2], redm[3]));
  float p = (j < N_) ? __expf(sc - m) : 0.f;
  s[tid] = p;
  float den = p;
  #pragma unroll
  for (int o = 32; o > 0; o >>= 1) den += __shfl_xor(den, o);
  if ((tid & 63) == 0) redd[tid >> 6] = den;
  __syncthreads();
  float dtot = redd[0] + redd[1] + redd[2] + redd[3];
  int lane = tid & 63, g = tid >> 6;
  float acc = 0.f;
  #pragma unroll 8
  for (int i = 0; i < CLS_CHSZ/4; ++i) {
    int jl = g + 4*i;
    int jj = c * CLS_CHSZ + jl;
    if (jj < N_) acc = fmaf(s[jl], bf2f(base[(size_t)jj * QKVC_ + 2*D_ + lane]), acc);
  }
  pvs[g][lane] = acc;
  __syncthreads();
  if (g == 0) {
    float pv = pvs[0][lane] + pvs[1][lane] + pvs[2][lane] + pvs[3][lane];
    float* pp = part + ((size_t)bh * CLS_CH + c) * 66;
    if (lane == 0) { pp[0] = m; pp[1] = dtot; }
    pp[2 + lane] = pv;
  }
}

__global__ __launch_bounds__(64) void cls_attn_reduce(const float* __restrict__ part,
                                                      unsigned short* __restrict__ att) {
  int bh = blockIdx.x;
  int b = bh / H_, h = bh % H_;
  int lane = threadIdx.x;
  const float* pp = part + (size_t)bh * CLS_CH * 66;
  float m = -1e30f;
  #pragma unroll
  for (int c = 0; c < CLS_CH; ++c) m = fmaxf(m, pp[c*66]);
  float den = 0.f, acc = 0.f;
  #pragma unroll
  for (int c = 0; c < CLS_CH; ++c) {
    float wfac = __expf(pp[c*66] - m);
    den += pp[c*66 + 1] * wfac;
    acc += pp[c*66 + 2 + lane] * wfac;
  }
  att[(size_t)(b * N_) * D_ + h * HD_ + lane] = f2bf(acc / den);
}

// ---------------------------------------------------------------- space attention (MFMA)
__global__ __launch_bounds__(256) void space_attn_mfma(const unsigned short* __restrict__ qkv,
                                                       unsigned short* __restrict__ att) {
  int blk = blockIdx.x;
  int f = blk % F_; int bh = blk / F_;
  int b = bh / H_, h = bh % H_;
  const unsigned short* qbase = qkv + (size_t)b * N_ * QKVC_ + h * HD_;
  __shared__ __align__(16) unsigned short Ksm[208*64];
  __shared__ __align__(16) unsigned short Vtm[64*256];
  __shared__ __align__(16) unsigned short Pm[4*16*256];
  int tid = threadIdx.x;

  for (int c = tid; c < 208*8; c += 256) {
    int j = c >> 3, cb = (c & 7) * 16;
    uint4 val = make_uint4(0,0,0,0);
    if (j < 197) {
      int n = (j == 0) ? 0 : (1 + f*P_ + j - 1);
      val = *(const uint4*)(qbase + (size_t)n*QKVC_ + D_ + cb/2);
    }
    *(uint4*)((char*)Ksm + j*128 + (cb ^ ((j&7)<<4))) = val;
  }
  for (int c = tid; c < 112*8; c += 256) {
    int jj = c % 112, dc = c / 112;
    int j0 = jj * 2;
    uint4 r0 = make_uint4(0,0,0,0), r1 = make_uint4(0,0,0,0);
    if (j0 < 197) {
      int n = (j0 == 0) ? 0 : (1 + f*P_ + j0 - 1);
      r0 = *(const uint4*)(qbase + (size_t)n*QKVC_ + 2*D_ + dc*8);
    }
    if (j0 + 1 < 197) {
      int n = 1 + f*P_ + j0;
      r1 = *(const uint4*)(qbase + (size_t)n*QKVC_ + 2*D_ + dc*8);
    }
    const unsigned short* e0 = (const unsigned short*)&r0;
    const unsigned short* e1 = (const unsigned short*)&r1;
    #pragma unroll
    for (int e = 0; e < 8; ++e) {
      int d = dc*8 + e;
      unsigned int pk = (unsigned int)e0[e] | ((unsigned int)e1[e] << 16);
      *(unsigned int*)((char*)Vtm + d*512 + ((2*j0) ^ ((d&7)<<4))) = pk;
    }
  }
  int w = tid >> 6, l = tid & 63;
  int fr = l & 15, fq = l >> 4;
  char* Pw = (char*)Pm + w * 8192;
  {
    int q = l >> 2, cb = 416 + (l & 3) * 8;
    *(unsigned long long*)(Pw + q*512 + (cb ^ ((q&7)<<4))) = 0ull;
  }
  __syncthreads();

  int swz = (fr & 7) << 4;
  for (int qt = w; qt <= 12; qt += 4) {
    int qrow = qt*16 + fr; if (qrow > 195) qrow = 195;
    int n_q = 1 + f*P_ + qrow;
    bf16x8 qf0 = *(const bf16x8*)(qbase + (size_t)n_q*QKVC_ + fq*8);
    bf16x8 qf1 = *(const bf16x8*)(qbase + (size_t)n_q*QKVC_ + 32 + fq*8);
    f32x4 s[13];
    #pragma unroll
    for (int jt = 0; jt < 13; ++jt) s[jt] = (f32x4){0.f,0.f,0.f,0.f};
    #pragma unroll
    for (int jt = 0; jt < 13; ++jt) {
      bf16x8 a0 = *(const bf16x8*)((char*)Ksm + (jt*16+fr)*128 + ((fq*16) ^ swz));
      s[jt] = __builtin_amdgcn_mfma_f32_16x16x32_bf16(a0, qf0, s[jt], 0, 0, 0);
      bf16x8 a1 = *(const bf16x8*)((char*)Ksm + (jt*16+fr)*128 + ((64 + fq*16) ^ swz));
      s[jt] = __builtin_amdgcn_mfma_f32_16x16x32_bf16(a1, qf1, s[jt], 0, 0, 0);
    }
    float m = -1e30f;
    #pragma unroll
    for (int jt = 0; jt < 13; ++jt) {
      #pragma unroll
      for (int r = 0; r < 4; ++r) {
        if (jt*16 + fq*4 + r < 197) m = fmaxf(m, s[jt][r]);
      }
    }
    m = fmaxf(m, __shfl_xor(m, 16));
    m = fmaxf(m, __shfl_xor(m, 32));
    float den = 0.f;
    #pragma unroll
    for (int jt = 0; jt < 13; ++jt) {
      #pragma unroll
      for (int r = 0; r < 4; ++r) {
        float p = (jt*16 + fq*4 + r < 197) ? __expf((s[jt][r] - m) * SCALE_) : 0.f;
        s[jt][r] = p;
        den += p;
      }
    }
    den += __shfl_xor(den, 16);
    den += __shfl_xor(den, 32);
    #pragma unroll
    for (int jt = 0; jt < 13; ++jt) {
      unsigned long long pv = (unsigned long long)pk2(s[jt][0], s[jt][1])
                            | ((unsigned long long)pk2(s[jt][2], s[jt][3]) << 32);
      *(unsigned long long*)(Pw + fr*512 + ((jt*32 + fq*8) ^ swz)) = pv;
    }
    float rden = 1.0f / den;
    bool wr_ok = (qt*16 + fr) < 196;
    int n_out = 1 + f*P_ + qt*16 + fr;
    #pragma unroll
    for (int dt = 0; dt < 4; ++dt) {
      f32x4 o = (f32x4){0.f,0.f,0.f,0.f};
      #pragma unroll
      for (int ks = 0; ks < 7; ++ks) {
        bf16x8 av = *(const bf16x8*)((char*)Vtm + (dt*16+fr)*512 + ((ks*64 + fq*16) ^ swz));
        bf16x8 bp = *(const bf16x8*)(Pw + fr*512 + ((ks*64 + fq*16) ^ swz));
        o = __builtin_amdgcn_mfma_f32_16x16x32_bf16(av, bp, o, 0, 0, 0);
      }
      if (wr_ok) {
        unsigned long long ov = (unsigned long long)pk2(o[0]*rden, o[1]*rden)
                              | ((unsigned long long)pk2(o[2]*rden, o[3]*rden) << 32);
        *(unsigned long long*)(att + (size_t)(b*N_ + n_out)*D_ + h*HD_ + dt*16 + fq*4) = ov;
      }
    }
  }
}

// ---------------------------------------------------------------- time attention (bf16 qkv)
__global__ __launch_bounds__(256) void time_attn_kernel(const unsigned short* __restrict__ qkv,
                                                        unsigned short* __restrict__ att) {
  int idx = blockIdx.x * 4 + (threadIdx.x >> 6);
  int bh = idx / P_, p = idx % P_;
  int b = bh / H_, h = bh % H_;
  int lane = threadIdx.x & 63;
  const unsigned short* base = qkv + (size_t)b * N_ * QKVC_ + h * HD_ + lane;
  float k[9], v[9];
  k[0] = bf2f(base[D_]);
  v[0] = bf2f(base[2*D_]);
  #pragma unroll
  for (int j = 0; j < 8; ++j) {
    size_t r = (size_t)(1 + j * P_ + p) * QKVC_;
    k[j+1] = bf2f(base[r + D_]);
    v[j+1] = bf2f(base[r + 2*D_]);
  }
  #pragma unroll 1
  for (int f = 0; f < F_; ++f) {
    size_t qr = (size_t)(1 + f * P_ + p) * QKVC_;
    float qd = bf2f(base[qr]) * SCALE_;
    float s[9];
    #pragma unroll
    for (int j = 0; j < 9; ++j) {
      float prod = qd * k[j];
      #pragma unroll
      for (int o = 32; o > 0; o >>= 1) prod += __shfl_xor(prod, o);
      s[j] = prod;
    }
    float m = s[0];
    #pragma unroll
    for (int j = 1; j < 9; ++j) m = fmaxf(m, s[j]);
    float den = 0.f, o_ = 0.f;
    #pragma unroll
    for (int j = 0; j < 9; ++j) {
      float pj = __expf(s[j] - m);
      den += pj;
      o_ = fmaf(pj, v[j], o_);
    }
    att[(size_t)(b * N_ + 1 + f * P_ + p) * D_ + h * HD_ + lane] = f2bf(o_ / den);
  }
}

// ---------------------------------------------------------------- launcher
extern "C" void kernel_launch(void* const* d_in, const int* in_sizes, int n_in,
                              void* d_out, int out_size, void* d_ws, size_t ws_size,
                              hipStream_t stream) {
  const float* x_in     = (const float*)d_in[0];
  const float* qkv_w_t  = (const float*)d_in[1];
  const float* proj_w_t = (const float*)d_in[2];
  const float* proj_b_t = (const float*)d_in[3];
  const float* qkv_w_s  = (const float*)d_in[4];
  const float* proj_w_s = (const float*)d_in[5];
  const float* proj_b_s = (const float*)d_in[6];
  const float* fc1_w    = (const float*)d_in[7];
  const float* fc1_b    = (const float*)d_in[8];
  const float* fc2_w    = (const float*)d_in[9];
  const float* fc2_b    = (const float*)d_in[10];
  const float* ln1_g    = (const float*)d_in[11];
  const float* ln1_b    = (const float*)d_in[12];
  const float* ln2_g    = (const float*)d_in[13];
  const float* ln2_b    = (const float*)d_in[14];
  const float* ln3_g    = (const float*)d_in[15];
  const float* ln3_b    = (const float*)d_in[16];

  float* X_out = (float*)d_out;
  char* ws = (char*)d_ws;
  unsigned short* Wbf = (unsigned short*)ws;
  const size_t WOFF = 18874368;
  unsigned short* QKVbf = (unsigned short*)(ws + WOFF);
  unsigned short* Hbf   = (unsigned short*)(ws + WOFF);
  float*          TR    = (float*)(ws + WOFF + 57839616);
  unsigned short* Abf   = (unsigned short*)(ws + WOFF + 57839616 + 19279872);
  float*          CLSP  = (float*)(ws + WOFF + 57839616 + 19279872 + 9639936);

  unsigned short* wqkv_t = Wbf + 0;
  unsigned short* wproj_t= Wbf + 1769472;
  unsigned short* wqkv_s = Wbf + 2359296;
  unsigned short* wproj_s= Wbf + 4128768;
  unsigned short* wfc1   = Wbf + 4718592;
  unsigned short* wfc2   = Wbf + 7077888;

  dim3 blk(256);
  dim3 g_qkv(50, 18), g_proj(50, 6), g_fc1(50, 24), g_fc2(50, 6);

  for (int l = 0; l < L_; ++l) {
    const float* X = (l == 0) ? x_in : (const float*)X_out;
    cvt_layer_kernel<<<2048, blk, 0, stream>>>(
        qkv_w_t + (size_t)l*SQKV, proj_w_t + (size_t)l*SPROJ,
        qkv_w_s + (size_t)l*SQKV, proj_w_s + (size_t)l*SPROJ,
        fc1_w + (size_t)l*SFC, fc2_w + (size_t)l*SFC, Wbf);
    // 1. a = LN3(x)
    ln_kernel<<<BN_, blk, 0, stream>>>(X, ln3_g + l*D_, ln3_b + l*D_, Abf);
    // 2. qkv_t (bf16 out)
    mfma_gemm<3><<<g_qkv, blk, 0, stream>>>(Abf, wqkv_t, nullptr, nullptr, QKVbf, BN_, QKVC_, D_);
    // 3/4. time attention (+ cls)
    cls_attn_part<<<B_*H_*CLS_CH, blk, 0, stream>>>(QKVbf, CLSP);
    cls_attn_reduce<<<B_*H_, dim3(64), 0, stream>>>(CLSP, Abf);
    time_attn_kernel<<<(B_*H_*P_)/4, blk, 0, stream>>>(QKVbf, Abf);
    // 5. time_residual = x + att @ proj_w_t^T + b
    mfma_gemm<1><<<g_proj, blk, 0, stream>>>(Abf, wproj_t, proj_b_t + l*D_, X, TR, BN_, D_, D_);
    // 6. a = LN1(time_residual)
    ln_kernel<<<BN_, blk, 0, stream>>>(TR, ln1_g + l*D_, ln1_b + l*D_, Abf);
    // 7. qkv_s (bf16 out)
    mfma_gemm<3><<<g_qkv, blk, 0, stream>>>(Abf, wqkv_s, nullptr, nullptr, QKVbf, BN_, QKVC_, D_);
    // 8/9. space attention (+ cls)
    cls_attn_part<<<B_*H_*CLS_CH, blk, 0, stream>>>(QKVbf, CLSP);
    cls_attn_reduce<<<B_*H_, dim3(64), 0, stream>>>(CLSP, Abf);
    space_attn_mfma<<<B_*H_*F_, blk, 0, stream>>>(QKVbf, Abf);
    // 10. space_residual = x + att @ proj_w_s^T + b
    mfma_gemm<1><<<g_proj, blk, 0, stream>>>(Abf, wproj_s, proj_b_s + l*D_, X, TR, BN_, D_, D_);
    // 11. a = LN2(space_residual)
    ln_kernel<<<BN_, blk, 0, stream>>>(TR, ln2_g + l*D_, ln2_b + l*D_, Abf);
    // 12. h = gelu(a @ fc1^T + b)  (bf16 out)
    mfma_gemm<2><<<g_fc1, blk, 0, stream>>>(Abf, wfc1, fc1_b + l*MLP_, nullptr, Hbf, BN_, MLP_, D_);
    // 13. out = space_residual + h @ fc2^T + b
    mfma_gemm<1><<<g_fc2, blk, 0, stream>>>(Hbf, wfc2, fc2_b + l*D_, TR, X_out, BN_, D_, MLP_);
  }
}